// Round 4
// baseline (1847.168 us; speedup 1.0000x reference)
//
#include <hip/hip_runtime.h>

// CharRNN fused: B=256, L=1024, V=40, H=128. One block/CU, 512 thr = 8 waves.
//
// R7 structure (resubmitted after infra failure; no counter data last round):
// k-parallel readlane broadcast (R6) + LDS-atomic K-reduction.
//   Wave w owns k in [16w,16w+16), lane k'<16 holds h[16w+k'] in hreg.
//   Per step: 16-iter readlane loop -> 3 fused dots (acc0 j=lane, acc1
//   j=lane+64, lacc v=lane<40). Partials are ds_add_f32'd straight into
//   hacc[p][j] (double-buffered, PRE-INITIALIZED with e_t + b_h one step
//   ahead), so the post-barrier reduce is ONE ds_read_b32 + tanh instead of
//   8 reads + 7 adds + e add. Each wave e-inits only its OWN 16-slice of the
//   other buffer (same-wave LDS ordering + the step barrier make this
//   race-free vs. other waves' atomics and reads).
//
// R6 post-mortem: VGPR_Count=52 => weights still parked outside arch VGPRs;
// the asm "+v" pins likely MANUFACTURED accvgpr copies each step. Pins
// removed this round; VGPR_Count is the diagnostic.

#define BB 256
#define LL 1024
#define VV 40
#define HH 128
#define WIN 16

__device__ __forceinline__ float fast_tanh(float x) {
    // tanh(x) = 1 - 2/(exp(2x)+1); overflow -> inf -> rcp -> 0 -> +1 (correct)
    float e = __expf(2.0f * x);
    float r = __builtin_amdgcn_rcpf(e + 1.0f);
    return 1.0f - 2.0f * r;
}

__device__ __forceinline__ float bcast(float v, int k) {
    return __int_as_float(__builtin_amdgcn_readlane(__float_as_int(v), k));
}

__global__ __launch_bounds__(512, 2) void rnn_fused(
    const int*   __restrict__ x,       // [B,L]
    const float* __restrict__ hidden,  // [B,H]
    const float* __restrict__ emb,     // [V,H]
    const float* __restrict__ Wh,      // [H,H]
    const float* __restrict__ Wo,      // [V,H]
    const float* __restrict__ b_h,     // [H]
    const float* __restrict__ b_y,     // [V]
    float*       __restrict__ out)     // [B*L*V logits][B*H final_hidden]
{
    __shared__ float emb_s[VV * HH];        // 20 KB (b_h folded in)
    __shared__ float hacc[2][HH];           //  1 KB  atomic accumulators (dbuf)
    __shared__ float lpart[WIN][8][48];     // 24 KB  logit partials (pad 40->48)
    __shared__ float bys[VV];
    __shared__ int   xbuf[LL];              //  4 KB
    // ~49.4 KB static LDS

    const int tid  = threadIdx.x;
    const int b    = blockIdx.x;
    const int w    = tid >> 6;          // wave 0..7
    const int lane = tid & 63;
    const int kq   = w << 4;            // wave's k-sixteenth base

    // ---- stage x, embedding(+b_h), b_y; pre-init hacc[0] = e_0 + b_h ----
    {
        const int4* xg = (const int4*)(x + (size_t)b * LL);
        int4* xs = (int4*)xbuf;
        for (int i = tid; i < LL / 4; i += 512) xs[i] = xg[i];
    }
    for (int i = tid; i < VV * HH; i += 512)
        emb_s[i] = emb[i] + b_h[i & (HH - 1)];
    if (tid < VV) bys[tid] = b_y[tid];
    if (tid < HH) {
        int x0 = x[(size_t)b * LL];
        hacc[0][tid] = emb[(size_t)x0 * HH + tid] + b_h[tid];
    }

    // ---- weights into registers (48 floats/lane) ----
    // wreg0[k] = Wh[lane][kq+k], wreg1[k] = Wh[lane+64][kq+k],
    // woreg[k] = Wo[min(lane,39)][kq+k]
    float wreg0[16], wreg1[16], woreg[16];
    {
        const float4* p0 = (const float4*)(Wh + (size_t)lane * HH + kq);
        const float4* p1 = (const float4*)(Wh + (size_t)(lane + 64) * HH + kq);
        int vrow = (lane < VV) ? lane : 0;
        const float4* p2 = (const float4*)(Wo + (size_t)vrow * HH + kq);
        #pragma unroll
        for (int i = 0; i < 4; i++) {
            float4 a = p0[i], c = p1[i], d = p2[i];
            wreg0[4*i+0] = a.x; wreg0[4*i+1] = a.y; wreg0[4*i+2] = a.z; wreg0[4*i+3] = a.w;
            wreg1[4*i+0] = c.x; wreg1[4*i+1] = c.y; wreg1[4*i+2] = c.z; wreg1[4*i+3] = c.w;
            woreg[4*i+0] = d.x; woreg[4*i+1] = d.y; woreg[4*i+2] = d.z; woreg[4*i+3] = d.w;
        }
    }
    float hreg = 0.f;
    if (lane < 16) hreg = hidden[(size_t)b * HH + kq + lane];
    __syncthreads();

    int p = 0;
    int idx_e = xbuf[1];   // x index feeding the e-init for step t+1

    for (int t = 0; t < LL; ++t) {
        // ---- broadcast k-loop: partials over my wave's k-sixteenth ----
        float acc0 = 0.f, acc1 = 0.f, lacc = 0.f;
        #pragma unroll
        for (int k = 0; k < 16; ++k) {
            float s = bcast(hreg, k);          // h_{t-1}[kq+k], VALU broadcast
            acc0 = fmaf(s, wreg0[k], acc0);    // j = lane
            acc1 = fmaf(s, wreg1[k], acc1);    // j = lane+64
            lacc = fmaf(s, woreg[k], lacc);    // v = lane (<40)
        }

        // ---- K-reduction via LDS float atomics (conflict-free addresses) ----
        atomicAdd(&hacc[p][lane],      acc0);
        atomicAdd(&hacc[p][lane + 64], acc1);

        // ---- e-init for NEXT step: my own slice of the other buffer.
        // Safe: my reduce-read of hacc[p^1] (prev iter tail) precedes this in
        // program order (same wave, LDS in-order); other waves' atomics to
        // hacc[p^1] are on the far side of the barrier below.
        if (lane < 16)
            hacc[p ^ 1][kq + lane] = emb_s[idx_e * HH + kq + lane];

        if (t != 0 && lane < VV) lpart[(t - 1) & (WIN - 1)][w][lane] = lacc;
        __syncthreads();

        // ---- reduce: ONE read + tanh (e and b_h already inside) ----
        if (lane < 16)
            hreg = fast_tanh(hacc[p][kq + lane]);

        int tn = t + 2; if (tn > LL - 1) tn = LL - 1;
        idx_e = xbuf[tn];

        // ---- burst: reduce+store logit rows [t-16, t) ----
        if (t >= WIN && (t & (WIN - 1)) == 0) {
            const int rbase = t - WIN;
            {
                int o  = tid;                  // 0..511
                int tp = o / 40;
                int v  = o - 40 * tp;
                float sm = bys[v];
                #pragma unroll
                for (int g = 0; g < 8; ++g) sm += lpart[tp][g][v];
                out[(size_t)b * LL * VV + (size_t)(rbase + tp) * VV + v] = sm;
            }
            if (tid < 128) {
                int o  = tid + 512;            // 512..639
                int tp = o / 40;
                int v  = o - 40 * tp;
                float sm = bys[v];
                #pragma unroll
                for (int g = 0; g < 8; ++g) sm += lpart[tp][g][v];
                out[(size_t)b * LL * VV + (size_t)(rbase + tp) * VV + v] = sm;
            }
            __syncthreads();   // next step's lpart[0] write must wait
        }

        p ^= 1;
    }

    // ---- epilogue: logits for row L-1 from final h, then last burst ----
    {
        float lacc = 0.f;
        #pragma unroll
        for (int k = 0; k < 16; ++k) {
            float s = bcast(hreg, k);
            lacc = fmaf(s, woreg[k], lacc);
        }
        if (lane < VV) lpart[(LL - 1) & (WIN - 1)][w][lane] = lacc;
        __syncthreads();
        const int rbase = LL - WIN;
        {
            int o  = tid;
            int tp = o / 40;
            int v  = o - 40 * tp;
            float sm = bys[v];
            #pragma unroll
            for (int g = 0; g < 8; ++g) sm += lpart[tp][g][v];
            out[(size_t)b * LL * VV + (size_t)(rbase + tp) * VV + v] = sm;
        }
        if (tid < 128) {
            int o  = tid + 512;
            int tp = o / 40;
            int v  = o - 40 * tp;
            float sm = bys[v];
            #pragma unroll
            for (int g = 0; g < 8; ++g) sm += lpart[tp][g][v];
            out[(size_t)b * LL * VV + (size_t)(rbase + tp) * VV + v] = sm;
        }
        // final hidden
        if (lane < 16)
            out[(size_t)BB * LL * VV + (size_t)b * HH + kq + lane] = hreg;
    }
}

extern "C" void kernel_launch(void* const* d_in, const int* in_sizes, int n_in,
                              void* d_out, int out_size, void* d_ws, size_t ws_size,
                              hipStream_t stream) {
    const int*   x      = (const int*)  d_in[0];
    const float* hidden = (const float*)d_in[1];
    const float* emb    = (const float*)d_in[2];
    const float* Wh     = (const float*)d_in[3];
    const float* Wo     = (const float*)d_in[4];
    const float* bh     = (const float*)d_in[5];
    const float* by     = (const float*)d_in[6];
    float*       out    = (float*)      d_out;

    rnn_fused<<<dim3(BB), dim3(512), 0, stream>>>(x, hidden, emb, Wh, Wo, bh, by, out);
}

// Round 5
// 590.932 us; speedup vs baseline: 3.1259x; 3.1259x over previous
//
#include <hip/hip_runtime.h>

// CharRNN fused: B=256, L=1024, V=40, H=128. One block/CU, 512 thr = 8 waves.
//
// R8 = R6 (560us, best) + vectorized K-reduction. R7's LDS float atomicAdd
// regressed 3.2x (CAS retry loop under 8-way contention) -- reverted.
//
// Structure: k-parallel readlane broadcast. Wave w owns k in [16w,16w+16),
// lane k'<16 holds h[16w+k'] in hreg. Per step: 16-iter readlane loop -> 3
// fused dots (acc0 j=lane, acc1 j=lane+64, lacc v=lane<40).
//
// R8 change (the one lever this round): the post-barrier reduce was 64
// serialized ds_read_b32 wave-ops (8 waves x 8 g-major reads) ~ 450 cyc of
// LDS pileup on the serial chain. Partials now stored J-MAJOR in two
// float4-row arrays partA/partB[2][128][4] so each lane reduces with TWO
// ds_read_b128 (16 wave-ops total). Write-side bank conflicts from the
// 16B row stride are killed by a g-slot XOR swizzle:
//     slot = (w&3) ^ ((j>>3)&3)
// (write banks 2-way = free; reads 2-way = free). The slot permutation
// within a row is harmless because the reduce SUMS all 4 components.
// Note (j+64)>>3 & 3 == (j>>3)&3, so acc0/acc1 share one slot value.

#define BB 256
#define LL 1024
#define VV 40
#define HH 128
#define WIN 16

__device__ __forceinline__ float fast_tanh(float x) {
    // tanh(x) = 1 - 2/(exp(2x)+1); overflow -> inf -> rcp -> 0 -> +1 (correct)
    float e = __expf(2.0f * x);
    float r = __builtin_amdgcn_rcpf(e + 1.0f);
    return 1.0f - 2.0f * r;
}

__device__ __forceinline__ float bcast(float v, int k) {
    return __int_as_float(__builtin_amdgcn_readlane(__float_as_int(v), k));
}

__global__ __launch_bounds__(512, 2) void rnn_fused(
    const int*   __restrict__ x,       // [B,L]
    const float* __restrict__ hidden,  // [B,H]
    const float* __restrict__ emb,     // [V,H]
    const float* __restrict__ Wh,      // [H,H]
    const float* __restrict__ Wo,      // [V,H]
    const float* __restrict__ b_h,     // [H]
    const float* __restrict__ b_y,     // [V]
    float*       __restrict__ out)     // [B*L*V logits][B*H final_hidden]
{
    __shared__ float emb_s[VV * HH];        // 20 KB (b_h folded in)
    __shared__ float partA[2][HH][4];       //  4 KB  partials g=0..3 (j-major)
    __shared__ float partB[2][HH][4];       //  4 KB  partials g=4..7 (j-major)
    __shared__ float lpart[WIN][8][48];     // 24 KB  logit partials (pad 40->48)
    __shared__ float bys[VV];
    __shared__ int   xbuf[LL];              //  4 KB
    // ~56.2 KB static LDS

    const int tid  = threadIdx.x;
    const int b    = blockIdx.x;
    const int w    = tid >> 6;          // wave 0..7
    const int lane = tid & 63;
    const int kq   = w << 4;            // wave's k-sixteenth base
    // swizzled slot for this wave's partial writes (same for j and j+64)
    const int sl   = (w & 3) ^ ((lane >> 3) & 3);

    // ---- stage x, embedding(+b_h), b_y ----
    {
        const int4* xg = (const int4*)(x + (size_t)b * LL);
        int4* xs = (int4*)xbuf;
        for (int i = tid; i < LL / 4; i += 512) xs[i] = xg[i];
    }
    for (int i = tid; i < VV * HH; i += 512)
        emb_s[i] = emb[i] + b_h[i & (HH - 1)];
    if (tid < VV) bys[tid] = b_y[tid];

    // ---- weights into registers (48 floats/lane) ----
    // wreg0[k] = Wh[lane][kq+k], wreg1[k] = Wh[lane+64][kq+k],
    // woreg[k] = Wo[min(lane,39)][kq+k]
    float wreg0[16], wreg1[16], woreg[16];
    {
        const float4* p0 = (const float4*)(Wh + (size_t)lane * HH + kq);
        const float4* p1 = (const float4*)(Wh + (size_t)(lane + 64) * HH + kq);
        int vrow = (lane < VV) ? lane : 0;
        const float4* p2 = (const float4*)(Wo + (size_t)vrow * HH + kq);
        #pragma unroll
        for (int i = 0; i < 4; i++) {
            float4 a = p0[i], c = p1[i], d = p2[i];
            wreg0[4*i+0] = a.x; wreg0[4*i+1] = a.y; wreg0[4*i+2] = a.z; wreg0[4*i+3] = a.w;
            wreg1[4*i+0] = c.x; wreg1[4*i+1] = c.y; wreg1[4*i+2] = c.z; wreg1[4*i+3] = c.w;
            woreg[4*i+0] = d.x; woreg[4*i+1] = d.y; woreg[4*i+2] = d.z; woreg[4*i+3] = d.w;
        }
    }
    float hreg = 0.f;
    if (lane < 16) hreg = hidden[(size_t)b * HH + kq + lane];
    __syncthreads();

    int p = 0;
    int idx_cur = xbuf[0];

    for (int t = 0; t < LL; ++t) {
        int tn = t + 1; if (tn > LL - 1) tn = LL - 1;
        int idx_next = xbuf[tn];
        // e for THIS step (issued early; k-loop hides the LDS latency)
        float e_cur = emb_s[idx_cur * HH + kq + (lane & 15)];

        // ---- broadcast k-loop: partials over my wave's k-sixteenth ----
        float acc0 = 0.f, acc1 = 0.f, lacc = 0.f;
        #pragma unroll
        for (int k = 0; k < 16; ++k) {
            float s = bcast(hreg, k);          // h_{t-1}[kq+k], VALU broadcast
            acc0 = fmaf(s, wreg0[k], acc0);    // j = lane
            acc1 = fmaf(s, wreg1[k], acc1);    // j = lane+64
            lacc = fmaf(s, woreg[k], lacc);    // v = lane (<40)
        }

        // ---- partials, j-major with swizzled g-slot (write banks 2-way) ----
        float (*pw)[4] = (w < 4) ? partA[p] : partB[p];
        pw[lane][sl]      = acc0;
        pw[lane + 64][sl] = acc1;
        if (t != 0 && lane < VV) lpart[(t - 1) & (WIN - 1)][w][lane] = lacc;
        __syncthreads();

        // ---- K-reduction + tanh: TWO b128 reads, sum order-independent ----
        if (lane < 16) {
            int j = kq + lane;
            float4 ra = *(const float4*)partA[p][j];
            float4 rb = *(const float4*)partB[p][j];
            float vsum = ((ra.x + ra.y) + (ra.z + ra.w))
                       + ((rb.x + rb.y) + (rb.z + rb.w));
            hreg = fast_tanh(vsum + e_cur);
        }

        // ---- burst: reduce+store logit rows [t-16, t) ----
        if (t >= WIN && (t & (WIN - 1)) == 0) {
            const int rbase = t - WIN;
            {
                int o  = tid;                  // 0..511
                int tp = o / 40;
                int v  = o - 40 * tp;
                float sm = bys[v];
                #pragma unroll
                for (int g = 0; g < 8; ++g) sm += lpart[tp][g][v];
                out[(size_t)b * LL * VV + (size_t)(rbase + tp) * VV + v] = sm;
            }
            if (tid < 128) {
                int o  = tid + 512;            // 512..639
                int tp = o / 40;
                int v  = o - 40 * tp;
                float sm = bys[v];
                #pragma unroll
                for (int g = 0; g < 8; ++g) sm += lpart[tp][g][v];
                out[(size_t)b * LL * VV + (size_t)(rbase + tp) * VV + v] = sm;
            }
            __syncthreads();   // next step's lpart[0] write must wait
        }

        idx_cur = idx_next;
        p ^= 1;
    }

    // ---- epilogue: logits for row L-1 from final h, then last burst ----
    {
        float lacc = 0.f;
        #pragma unroll
        for (int k = 0; k < 16; ++k) {
            float s = bcast(hreg, k);
            lacc = fmaf(s, woreg[k], lacc);
        }
        if (lane < VV) lpart[(LL - 1) & (WIN - 1)][w][lane] = lacc;
        __syncthreads();
        const int rbase = LL - WIN;
        {
            int o  = tid;
            int tp = o / 40;
            int v  = o - 40 * tp;
            float sm = bys[v];
            #pragma unroll
            for (int g = 0; g < 8; ++g) sm += lpart[tp][g][v];
            out[(size_t)b * LL * VV + (size_t)(rbase + tp) * VV + v] = sm;
        }
        if (tid < 128) {
            int o  = tid + 512;
            int tp = o / 40;
            int v  = o - 40 * tp;
            float sm = bys[v];
            #pragma unroll
            for (int g = 0; g < 8; ++g) sm += lpart[tp][g][v];
            out[(size_t)b * LL * VV + (size_t)(rbase + tp) * VV + v] = sm;
        }
        // final hidden
        if (lane < 16)
            out[(size_t)BB * LL * VV + (size_t)b * HH + kq + lane] = hreg;
    }
}

extern "C" void kernel_launch(void* const* d_in, const int* in_sizes, int n_in,
                              void* d_out, int out_size, void* d_ws, size_t ws_size,
                              hipStream_t stream) {
    const int*   x      = (const int*)  d_in[0];
    const float* hidden = (const float*)d_in[1];
    const float* emb    = (const float*)d_in[2];
    const float* Wh     = (const float*)d_in[3];
    const float* Wo     = (const float*)d_in[4];
    const float* bh     = (const float*)d_in[5];
    const float* by     = (const float*)d_in[6];
    float*       out    = (float*)      d_out;

    rnn_fused<<<dim3(BB), dim3(512), 0, stream>>>(x, hidden, emb, Wh, Wo, bh, by, out);
}

// Round 6
// 586.749 us; speedup vs baseline: 3.1481x; 1.0071x over previous
//
#include <hip/hip_runtime.h>

// CharRNN fused: B=256, L=1024, V=40, H=128. One block/CU, 512 thr = 8 waves.
//
// R9 = R8 (548us, best) + AGPR eviction + split accumulator chains.
//
// R8 post-mortem: VALUBusy 59% at 1286 cyc/step implies ~190 instrs/wave/step
// vs ~103 in source -- 2x phantom issue. Mechanism: VGPR_Count=52 cannot hold
// the 48 persistent weights + ~25 live temps => weights live in AGPRs, and
// (almost) every weight FMA pays a v_accvgpr_read on the critical kloop chain.
// Root cause suspected: __launch_bounds__(512,2) caps unified budget at 256
// and the allocator splits arch/acc pessimistically. We always run exactly
// 1 block/CU (grid=256=CU count), so min-waves=2 buys nothing.
//   Fix 1: __launch_bounds__(512, 1) -> 512-reg budget. Diagnostic: VGPR_Count
//          should jump to ~80-110 and VALUBusy drop toward ~35-45%.
//   Fix 2: kloop accumulators split 4-way per dot (a0..a3/b0..b3/l0..l3),
//          readlanes issued 4-independent at a time: FMA dep chain 16 -> 4.
//
// Structure (unchanged from R8): k-parallel readlane broadcast. Wave w owns
// k in [16w,16w+16), lane k'<16 holds h[16w+k'] in hreg. Per step: 16-iter
// readlane loop -> 3 fused dots (acc0 j=lane, acc1 j=lane+64, lacc v=lane<40).
// Partials j-major with g-slot XOR swizzle; reduce = two ds_read_b128.

#define BB 256
#define LL 1024
#define VV 40
#define HH 128
#define WIN 16

__device__ __forceinline__ float fast_tanh(float x) {
    // tanh(x) = 1 - 2/(exp(2x)+1); overflow -> inf -> rcp -> 0 -> +1 (correct)
    float e = __expf(2.0f * x);
    float r = __builtin_amdgcn_rcpf(e + 1.0f);
    return 1.0f - 2.0f * r;
}

__device__ __forceinline__ float bcast(float v, int k) {
    return __int_as_float(__builtin_amdgcn_readlane(__float_as_int(v), k));
}

__global__ __launch_bounds__(512, 1) void rnn_fused(
    const int*   __restrict__ x,       // [B,L]
    const float* __restrict__ hidden,  // [B,H]
    const float* __restrict__ emb,     // [V,H]
    const float* __restrict__ Wh,      // [H,H]
    const float* __restrict__ Wo,      // [V,H]
    const float* __restrict__ b_h,     // [H]
    const float* __restrict__ b_y,     // [V]
    float*       __restrict__ out)     // [B*L*V logits][B*H final_hidden]
{
    __shared__ float emb_s[VV * HH];        // 20 KB (b_h folded in)
    __shared__ float partA[2][HH][4];       //  4 KB  partials g=0..3 (j-major)
    __shared__ float partB[2][HH][4];       //  4 KB  partials g=4..7 (j-major)
    __shared__ float lpart[WIN][8][48];     // 24 KB  logit partials (pad 40->48)
    __shared__ float bys[VV];
    __shared__ int   xbuf[LL];              //  4 KB
    // ~56.2 KB static LDS

    const int tid  = threadIdx.x;
    const int b    = blockIdx.x;
    const int w    = tid >> 6;          // wave 0..7
    const int lane = tid & 63;
    const int kq   = w << 4;            // wave's k-sixteenth base
    // swizzled slot for this wave's partial writes (same for j and j+64)
    const int sl   = (w & 3) ^ ((lane >> 3) & 3);

    // ---- stage x, embedding(+b_h), b_y ----
    {
        const int4* xg = (const int4*)(x + (size_t)b * LL);
        int4* xs = (int4*)xbuf;
        for (int i = tid; i < LL / 4; i += 512) xs[i] = xg[i];
    }
    for (int i = tid; i < VV * HH; i += 512)
        emb_s[i] = emb[i] + b_h[i & (HH - 1)];
    if (tid < VV) bys[tid] = b_y[tid];

    // ---- weights into registers (48 floats/lane) ----
    // wreg0[k] = Wh[lane][kq+k], wreg1[k] = Wh[lane+64][kq+k],
    // woreg[k] = Wo[min(lane,39)][kq+k]
    float wreg0[16], wreg1[16], woreg[16];
    {
        const float4* p0 = (const float4*)(Wh + (size_t)lane * HH + kq);
        const float4* p1 = (const float4*)(Wh + (size_t)(lane + 64) * HH + kq);
        int vrow = (lane < VV) ? lane : 0;
        const float4* p2 = (const float4*)(Wo + (size_t)vrow * HH + kq);
        #pragma unroll
        for (int i = 0; i < 4; i++) {
            float4 a = p0[i], c = p1[i], d = p2[i];
            wreg0[4*i+0] = a.x; wreg0[4*i+1] = a.y; wreg0[4*i+2] = a.z; wreg0[4*i+3] = a.w;
            wreg1[4*i+0] = c.x; wreg1[4*i+1] = c.y; wreg1[4*i+2] = c.z; wreg1[4*i+3] = c.w;
            woreg[4*i+0] = d.x; woreg[4*i+1] = d.y; woreg[4*i+2] = d.z; woreg[4*i+3] = d.w;
        }
    }
    float hreg = 0.f;
    if (lane < 16) hreg = hidden[(size_t)b * HH + kq + lane];
    __syncthreads();

    int p = 0;
    int idx_cur = xbuf[0];

    for (int t = 0; t < LL; ++t) {
        int tn = t + 1; if (tn > LL - 1) tn = LL - 1;
        int idx_next = xbuf[tn];
        // e for THIS step (issued early; k-loop hides the LDS latency)
        float e_cur = emb_s[idx_cur * HH + kq + (lane & 15)];

        // ---- broadcast k-loop: 4-way split accumulators, readlanes x4 ----
        float a0 = 0.f, a1 = 0.f, a2 = 0.f, a3 = 0.f;
        float c0 = 0.f, c1 = 0.f, c2 = 0.f, c3 = 0.f;
        float l0 = 0.f, l1 = 0.f, l2 = 0.f, l3 = 0.f;
        #pragma unroll
        for (int k = 0; k < 16; k += 4) {
            float s0 = bcast(hreg, k);
            float s1 = bcast(hreg, k + 1);
            float s2 = bcast(hreg, k + 2);
            float s3 = bcast(hreg, k + 3);
            a0 = fmaf(s0, wreg0[k],     a0);
            a1 = fmaf(s1, wreg0[k + 1], a1);
            a2 = fmaf(s2, wreg0[k + 2], a2);
            a3 = fmaf(s3, wreg0[k + 3], a3);
            c0 = fmaf(s0, wreg1[k],     c0);
            c1 = fmaf(s1, wreg1[k + 1], c1);
            c2 = fmaf(s2, wreg1[k + 2], c2);
            c3 = fmaf(s3, wreg1[k + 3], c3);
            l0 = fmaf(s0, woreg[k],     l0);
            l1 = fmaf(s1, woreg[k + 1], l1);
            l2 = fmaf(s2, woreg[k + 2], l2);
            l3 = fmaf(s3, woreg[k + 3], l3);
        }
        float acc0 = (a0 + a1) + (a2 + a3);
        float acc1 = (c0 + c1) + (c2 + c3);
        float lacc = (l0 + l1) + (l2 + l3);

        // ---- partials, j-major with swizzled g-slot (write banks 2-way) ----
        float (*pw)[4] = (w < 4) ? partA[p] : partB[p];
        pw[lane][sl]      = acc0;
        pw[lane + 64][sl] = acc1;
        if (t != 0 && lane < VV) lpart[(t - 1) & (WIN - 1)][w][lane] = lacc;
        __syncthreads();

        // ---- K-reduction + tanh: TWO b128 reads, sum order-independent ----
        if (lane < 16) {
            int j = kq + lane;
            float4 ra = *(const float4*)partA[p][j];
            float4 rb = *(const float4*)partB[p][j];
            float vsum = ((ra.x + ra.y) + (ra.z + ra.w))
                       + ((rb.x + rb.y) + (rb.z + rb.w));
            hreg = fast_tanh(vsum + e_cur);
        }

        // ---- burst: reduce+store logit rows [t-16, t) ----
        if (t >= WIN && (t & (WIN - 1)) == 0) {
            const int rbase = t - WIN;
            {
                int o  = tid;                  // 0..511
                int tp = o / 40;
                int v  = o - 40 * tp;
                float sm = bys[v];
                #pragma unroll
                for (int g = 0; g < 8; ++g) sm += lpart[tp][g][v];
                out[(size_t)b * LL * VV + (size_t)(rbase + tp) * VV + v] = sm;
            }
            if (tid < 128) {
                int o  = tid + 512;            // 512..639
                int tp = o / 40;
                int v  = o - 40 * tp;
                float sm = bys[v];
                #pragma unroll
                for (int g = 0; g < 8; ++g) sm += lpart[tp][g][v];
                out[(size_t)b * LL * VV + (size_t)(rbase + tp) * VV + v] = sm;
            }
            __syncthreads();   // next step's lpart[0] write must wait
        }

        idx_cur = idx_next;
        p ^= 1;
    }

    // ---- epilogue: logits for row L-1 from final h, then last burst ----
    {
        float l0 = 0.f, l1 = 0.f, l2 = 0.f, l3 = 0.f;
        #pragma unroll
        for (int k = 0; k < 16; k += 4) {
            l0 = fmaf(bcast(hreg, k),     woreg[k],     l0);
            l1 = fmaf(bcast(hreg, k + 1), woreg[k + 1], l1);
            l2 = fmaf(bcast(hreg, k + 2), woreg[k + 2], l2);
            l3 = fmaf(bcast(hreg, k + 3), woreg[k + 3], l3);
        }
        float lacc = (l0 + l1) + (l2 + l3);
        if (lane < VV) lpart[(LL - 1) & (WIN - 1)][w][lane] = lacc;
        __syncthreads();
        const int rbase = LL - WIN;
        {
            int o  = tid;
            int tp = o / 40;
            int v  = o - 40 * tp;
            float sm = bys[v];
            #pragma unroll
            for (int g = 0; g < 8; ++g) sm += lpart[tp][g][v];
            out[(size_t)b * LL * VV + (size_t)(rbase + tp) * VV + v] = sm;
        }
        if (tid < 128) {
            int o  = tid + 512;
            int tp = o / 40;
            int v  = o - 40 * tp;
            float sm = bys[v];
            #pragma unroll
            for (int g = 0; g < 8; ++g) sm += lpart[tp][g][v];
            out[(size_t)b * LL * VV + (size_t)(rbase + tp) * VV + v] = sm;
        }
        // final hidden
        if (lane < 16)
            out[(size_t)BB * LL * VV + (size_t)b * HH + kq + lane] = hreg;
    }
}

extern "C" void kernel_launch(void* const* d_in, const int* in_sizes, int n_in,
                              void* d_out, int out_size, void* d_ws, size_t ws_size,
                              hipStream_t stream) {
    const int*   x      = (const int*)  d_in[0];
    const float* hidden = (const float*)d_in[1];
    const float* emb    = (const float*)d_in[2];
    const float* Wh     = (const float*)d_in[3];
    const float* Wo     = (const float*)d_in[4];
    const float* bh     = (const float*)d_in[5];
    const float* by     = (const float*)d_in[6];
    float*       out    = (float*)      d_out;

    rnn_fused<<<dim3(BB), dim3(512), 0, stream>>>(x, hidden, emb, Wh, Wo, bh, by, out);
}